// Round 1
// baseline (424.724 us; speedup 1.0000x reference)
//
#include <hip/hip_runtime.h>

#define B_   8
#define N_   307
#define BN   (B_ * N_)          // 2456 blocks
#define OUT_ELEMS (BN * 64 * 64) // 10,059,776 floats (out), scores follow

typedef float f32x4 __attribute__((ext_vector_type(4)));
typedef short s16x8 __attribute__((ext_vector_type(8)));

__device__ __forceinline__ unsigned short f2bf(float x) {
    unsigned int u = __builtin_bit_cast(unsigned int, x);
    u += 0x7FFFu + ((u >> 16) & 1u);        // round-to-nearest-even
    return (unsigned short)(u >> 16);
}

__device__ __forceinline__ s16x8 ldfrag(const unsigned short* p) {
    return *reinterpret_cast<const s16x8*>(p);
}

// 64x64 row-major fp32 -> bf16 A-operand fragment layout [mtile][kiter][lane][8]
// A element (m, k): mtile=m>>4, kiter=k>>5, lane=((k>>3)&3)*16 + (m&15), j=k&7
__device__ __forceinline__ void stage_A(const float* __restrict__ src,
                                        unsigned short* dst, int tid) {
    const float4* s4 = reinterpret_cast<const float4*>(src);
#pragma unroll
    for (int i = 0; i < 4; ++i) {
        int idx = i * 256 + tid;          // float4 index, 1024 total
        float4 v = s4[idx];
        int m  = idx >> 4;
        int f0 = (idx & 15) << 2;         // 4-aligned, same quad-of-8
        int mt = m >> 4;
        int ki = f0 >> 5;
        int qd = (f0 >> 3) & 3;
        int j0 = f0 & 7;                  // 0 or 4
        unsigned short* p = dst + ((((mt * 2 + ki) * 64) + (qd << 4) + (m & 15)) << 3) + j0;
        short4 pk;
        pk.x = (short)f2bf(v.x); pk.y = (short)f2bf(v.y);
        pk.z = (short)f2bf(v.z); pk.w = (short)f2bf(v.w);
        *reinterpret_cast<short4*>(p) = pk;
    }
}

// 64x64 row-major fp32 (K x N) -> bf16 B-operand fragment layout [ntile][kiter][lane][8]
// B element (k, n): ntile=n>>4, kiter=k>>5, lane=((k>>3)&3)*16 + (n&15), j=k&7
__device__ __forceinline__ void stage_B(const float* __restrict__ src,
                                        unsigned short* dst, int tid) {
    const float4* s4 = reinterpret_cast<const float4*>(src);
#pragma unroll
    for (int i = 0; i < 4; ++i) {
        int idx = i * 256 + tid;
        float4 v = s4[idx];
        int k  = idx >> 4;
        int n0 = (idx & 15) << 2;
        int ki = k >> 5;
        int qd = (k >> 3) & 3;
        int j  = k & 7;
        float vv[4] = {v.x, v.y, v.z, v.w};
#pragma unroll
        for (int c = 0; c < 4; ++c) {
            int n = n0 + c;
            dst[((((n >> 4) * 2 + ki) * 64 + (qd << 4) + (n & 15)) << 3) + j] = f2bf(vv[c]);
        }
    }
}

__global__ __launch_bounds__(256, 2) void mta_kernel(
    const float* __restrict__ Xq, const float* __restrict__ Xk,
    const float* __restrict__ Xv, const float* __restrict__ maskp,
    const float* __restrict__ res, const float* __restrict__ Wq,
    const float* __restrict__ Wk, const float* __restrict__ Wv,
    const float* __restrict__ Wfc, const float* __restrict__ lnS,
    const float* __restrict__ lnB, float* __restrict__ out,
    float* __restrict__ scores_out)
{
    // LDS carve (58.3 KB), phase-aliased:
    //  sQf/sKf: scores A/B frags (quads 0-1 only, K zero-padded via zero regs)
    //  sXC: X frags (proj) -> ctx frags (fc);  sWA: W frags (proj/fc) -> attn frags (PV)
    __shared__ __align__(16) unsigned char smem[59904];
    unsigned short* sQf = (unsigned short*)(smem);           // 8KB [h][mt][32][8]
    unsigned short* sKf = (unsigned short*)(smem + 8192);    // 8KB [h][nt][32][8]
    unsigned short* sVf = (unsigned short*)(smem + 16384);   // 8KB [h][ki][64][8]
    unsigned short* sXC = (unsigned short*)(smem + 24576);   // 8KB A-frags
    unsigned short* sWA = (unsigned short*)(smem + 32768);   // 8KB B-frags / attn A-frags
    float* sS    = (float*)(smem + 40960);                   // 16KB 64x64 scores tile
    float* sRed  = (float*)(smem + 57344);                   // 1KB
    float* sSum  = (float*)(smem + 58368);                   // 1KB
    float* sMask = (float*)(smem + 59392);                   // 256B

    const int bn   = blockIdx.x;
    const int tid  = threadIdx.x;
    const int w    = tid >> 6;       // wave = row mtile
    const int lane = tid & 63;
    const int quad = lane >> 4;
    const int l16  = lane & 15;
    const size_t base64 = (size_t)bn * 4096;

    if (tid < 64) sMask[tid] = maskp[bn * 64 + tid];

    // ---------------- Projections: Q (scaled 1/4), K, V ----------------
#pragma unroll 1
    for (int pj = 0; pj < 3; ++pj) {
        const float* Xs = (pj == 0) ? Xq : (pj == 1) ? Xk : Xv;
        const float* Ws = (pj == 0) ? Wq : (pj == 1) ? Wk : Wv;
        stage_A(Xs + base64, sXC, tid);
        stage_B(Ws, sWA, tid);
        __syncthreads();
        s16x8 a0 = ldfrag(sXC + (((w * 2 + 0) * 64 + lane) << 3));
        s16x8 a1 = ldfrag(sXC + (((w * 2 + 1) * 64 + lane) << 3));
#pragma unroll
        for (int nt = 0; nt < 4; ++nt) {
            f32x4 acc = {0.f, 0.f, 0.f, 0.f};
            s16x8 b0 = ldfrag(sWA + (((nt * 2 + 0) * 64 + lane) << 3));
            s16x8 b1 = ldfrag(sWA + (((nt * 2 + 1) * 64 + lane) << 3));
            acc = __builtin_amdgcn_mfma_f32_16x16x32_bf16(a0, b0, acc, 0, 0, 0);
            acc = __builtin_amdgcn_mfma_f32_16x16x32_bf16(a1, b1, acc, 0, 0, 0);
            // writeback: element (row = w*16 + quad*4 + r, col e = nt*16 + l16)
            if (pj == 0) {          // Q -> scores A-frag layout, fold 1/sqrt(16)
#pragma unroll
                for (int r = 0; r < 4; ++r) {
                    int q15 = quad * 4 + r;
                    sQf[(((nt * 4 + w) * 32 + ((l16 >> 3) << 4) + q15) << 3) + (l16 & 7)]
                        = f2bf(acc[r] * 0.25f);
                }
            } else if (pj == 1) {   // K -> scores B-frag layout
#pragma unroll
                for (int r = 0; r < 4; ++r) {
                    int k15 = quad * 4 + r;
                    sKf[(((nt * 4 + w) * 32 + ((l16 >> 3) << 4) + k15) << 3) + (l16 & 7)]
                        = f2bf(acc[r]);
                }
            } else {                // V -> PV B-frag layout
#pragma unroll
                for (int r = 0; r < 4; ++r) {
                    int kk = w * 16 + quad * 4 + r;
                    sVf[(((nt * 2 + (kk >> 5)) * 64 + (((kk >> 3) & 3) << 4) + l16) << 3)
                        + (kk & 7)] = f2bf(acc[r]);
                }
            }
        }
        __syncthreads();
    }

    // ---------------- Attention (per head) ----------------
    f32x4 ctx[4];
#pragma unroll
    for (int h = 0; h < 4; ++h) ctx[h] = {0.f, 0.f, 0.f, 0.f};

    const s16x8 zf = {0, 0, 0, 0, 0, 0, 0, 0};
#pragma unroll 1
    for (int h = 0; h < 4; ++h) {
        const size_t sbase = ((size_t)(bn * 4 + h)) << 12;
        const float4* r4 = (const float4*)(res + sbase);
        float4* s4 = (float4*)sS;
#pragma unroll
        for (int i = 0; i < 4; ++i) s4[i * 256 + tid] = r4[i * 256 + tid];  // stage res_att
        __syncthreads();

        // scores = (Q/4)·K^T + res ; K=16 zero-padded to 32 (lanes>=32 get zero frags)
        s16x8 aq = zf;
        if (lane < 32) aq = ldfrag(sQf + (((h * 4 + w) * 32 + lane) << 3));
        f32x4 sacc[4];
#pragma unroll
        for (int nt = 0; nt < 4; ++nt) {
            s16x8 bk = zf;
            if (lane < 32) bk = ldfrag(sKf + (((h * 4 + nt) * 32 + lane) << 3));
            f32x4 t = {0.f, 0.f, 0.f, 0.f};
            sacc[nt] = __builtin_amdgcn_mfma_f32_16x16x32_bf16(aq, bk, t, 0, 0, 0);
        }
#pragma unroll
        for (int nt = 0; nt < 4; ++nt) {
#pragma unroll
            for (int r = 0; r < 4; ++r) {
                int q  = w * 16 + quad * 4 + r;
                int fl = q * 64 + nt * 16 + l16;
                float s = sacc[nt][r] + sS[fl];
                s = (sMask[q] > 0.5f) ? -1e9f : s;   // mask whole q row
                sS[fl] = s;
            }
        }
        __syncthreads();

        // coalesced global write of masked scores + column-softmax (over q, axis=3)
        float4* o4 = (float4*)(scores_out + sbase);
#pragma unroll
        for (int i = 0; i < 4; ++i) o4[i * 256 + tid] = s4[i * 256 + tid];
        const int kk = tid & 63, part = tid >> 6, q0 = part * 16;
        float mx = -3.0e38f;
#pragma unroll
        for (int qq = 0; qq < 16; ++qq) mx = fmaxf(mx, sS[(q0 + qq) * 64 + kk]);
        sRed[part * 64 + kk] = mx;
        __syncthreads();
        mx = fmaxf(fmaxf(sRed[kk], sRed[64 + kk]), fmaxf(sRed[128 + kk], sRed[192 + kk]));
        float ss = 0.f;
#pragma unroll
        for (int qq = 0; qq < 16; ++qq) ss += __expf(sS[(q0 + qq) * 64 + kk] - mx);
        sSum[part * 64 + kk] = ss;
        __syncthreads();
        float tot = sSum[kk] + sSum[64 + kk] + sSum[128 + kk] + sSum[192 + kk];
        float inv = 1.0f / tot;
#pragma unroll
        for (int qq = 0; qq < 16; ++qq) {
            int q = q0 + qq;
            float a = __expf(sS[q * 64 + kk] - mx) * inv;
            // attn -> PV A-frag layout (into sWA, aliasing dead W frags)
            sWA[((((q >> 4) * 2 + (kk >> 5)) * 64 + (((kk >> 3) & 3) << 4) + (q & 15)) << 3)
                + (kk & 7)] = f2bf(a);
        }
        __syncthreads();

        // PV: ctx_h += attn · V_h
#pragma unroll
        for (int ki = 0; ki < 2; ++ki) {
            s16x8 ap = ldfrag(sWA + (((w * 2 + ki) * 64 + lane) << 3));
            s16x8 bv = ldfrag(sVf + (((h * 2 + ki) * 64 + lane) << 3));
            ctx[h] = __builtin_amdgcn_mfma_f32_16x16x32_bf16(ap, bv, ctx[h], 0, 0, 0);
        }
        __syncthreads();   // protects sWA/sS before next head / fc staging
    }

    // ---------------- fc + residual + layernorm ----------------
    // ctx -> fc A-frag layout (into sXC, dead since projections)
#pragma unroll
    for (int h = 0; h < 4; ++h) {
        int c  = h * 16 + l16;
        int hi = (w * 2 + (c >> 5)) * 64 + (((c >> 3) & 3) << 4);
#pragma unroll
        for (int r = 0; r < 4; ++r) {
            sXC[((hi + quad * 4 + r) << 3) + (c & 7)] = f2bf(ctx[h][r]);
        }
    }
    stage_B(Wfc, sWA, tid);
    __syncthreads();

    f32x4 oacc[4];
    {
        s16x8 a0 = ldfrag(sXC + (((w * 2 + 0) * 64 + lane) << 3));
        s16x8 a1 = ldfrag(sXC + (((w * 2 + 1) * 64 + lane) << 3));
#pragma unroll
        for (int nt = 0; nt < 4; ++nt) {
            f32x4 acc = {0.f, 0.f, 0.f, 0.f};
            s16x8 b0 = ldfrag(sWA + (((nt * 2 + 0) * 64 + lane) << 3));
            s16x8 b1 = ldfrag(sWA + (((nt * 2 + 1) * 64 + lane) << 3));
            acc = __builtin_amdgcn_mfma_f32_16x16x32_bf16(a0, b0, acc, 0, 0, 0);
            acc = __builtin_amdgcn_mfma_f32_16x16x32_bf16(a1, b1, acc, 0, 0, 0);
            oacc[nt] = acc;
        }
    }

    float scl[4], bia[4];
#pragma unroll
    for (int nt = 0; nt < 4; ++nt) {
        scl[nt] = lnS[nt * 16 + l16];
        bia[nt] = lnB[nt * 16 + l16];
    }
#pragma unroll
    for (int r = 0; r < 4; ++r) {
        int q = w * 16 + quad * 4 + r;
        float px[4], sum = 0.f, sq = 0.f;
#pragma unroll
        for (int nt = 0; nt < 4; ++nt) {
            float x = oacc[nt][r] + Xq[base64 + q * 64 + nt * 16 + l16];
            px[nt] = x; sum += x; sq += x * x;
        }
        // row of 64 lives on the 16 lanes of this quad (4 vals each): xor-reduce
#pragma unroll
        for (int m = 1; m <= 8; m <<= 1) {
            sum += __shfl_xor(sum, m, 64);
            sq  += __shfl_xor(sq,  m, 64);
        }
        float mu   = sum * 0.015625f;
        float var  = sq * 0.015625f - mu * mu;
        float rstd = rsqrtf(var + 1e-5f);
#pragma unroll
        for (int nt = 0; nt < 4; ++nt) {
            out[base64 + q * 64 + nt * 16 + l16] = (px[nt] - mu) * rstd * scl[nt] + bia[nt];
        }
    }
}

extern "C" void kernel_launch(void* const* d_in, const int* in_sizes, int n_in,
                              void* d_out, int out_size, void* d_ws, size_t ws_size,
                              hipStream_t stream) {
    const float* Xq   = (const float*)d_in[0];
    const float* Xk   = (const float*)d_in[1];
    const float* Xv   = (const float*)d_in[2];
    const float* msk  = (const float*)d_in[3];
    const float* res  = (const float*)d_in[4];
    const float* Wq   = (const float*)d_in[5];
    const float* Wk   = (const float*)d_in[6];
    const float* Wv   = (const float*)d_in[7];
    const float* Wfc  = (const float*)d_in[8];
    const float* lnS  = (const float*)d_in[9];
    const float* lnB  = (const float*)d_in[10];
    float* out    = (float*)d_out;
    float* scores = out + OUT_ELEMS;
    mta_kernel<<<BN, 256, 0, stream>>>(Xq, Xk, Xv, msk, res, Wq, Wk, Wv, Wfc,
                                       lnS, lnB, out, scores);
}